// Round 8
// baseline (151.446 us; speedup 1.0000x reference)
//
#include <hip/hip_runtime.h>
#include <hip/hip_bf16.h>
#include <stdint.h>

typedef __bf16 bf16_t;
typedef __bf16 bf16x4 __attribute__((ext_vector_type(4)));
typedef __bf16 bf16x8 __attribute__((ext_vector_type(8)));
typedef float  f32x4  __attribute__((ext_vector_type(4)));

#define QK_SCALE 0.1803368801111204f   /* 0.125 * log2(e): softmax in log2 domain */

// async global->LDS, 16B per lane. LDS dest must be wave-uniform base (+lane*16 by HW).
__device__ __forceinline__ void gload_lds16(const void* g, void* l) {
    __builtin_amdgcn_global_load_lds(
        (__attribute__((address_space(1))) unsigned int*)(uintptr_t)g,
        (__attribute__((address_space(3))) unsigned int*)(uint32_t)(uintptr_t)l,
        16, 0, 0);
}

// ---------------- kernel 1: fp32 -> bf16 conversion / weight packing ----------
__global__ __launch_bounds__(256) void convert_kernel(
    const float* __restrict__ emb, const float* __restrict__ wq,
    const float* __restrict__ wk,  const float* __restrict__ wv,
    bf16_t* __restrict__ embb, bf16_t* __restrict__ wcat)
{
    size_t base = ((size_t)blockIdx.x * 256 + threadIdx.x) * 8;
    const float* src;
    bf16_t* dst;
    if (base < (size_t)4194304) { src = emb + base; dst = embb + base; }
    else {
        size_t r = base - 4194304;
        int wsel = (int)(r >> 20);
        size_t off = r & 1048575;
        src = (wsel == 0 ? wq : (wsel == 1 ? wk : wv)) + off;
        dst = wcat + r;
    }
    float4 a  = *(const float4*)src;
    float4 c2 = *(const float4*)(src + 4);
    bf16x8 o;
    o[0]=(bf16_t)a.x;  o[1]=(bf16_t)a.y;  o[2]=(bf16_t)a.z;  o[3]=(bf16_t)a.w;
    o[4]=(bf16_t)c2.x; o[5]=(bf16_t)c2.y; o[6]=(bf16_t)c2.z; o[7]=(bf16_t)c2.w;
    *(bf16x8*)dst = o;
}

// ---------------- kernel 2: QKV projection (NT GEMM, 3-buf counted-vmcnt) -----
// C[4096][3072] = A[4096][1024] * Wc[3072][1024]^T
// q,k: [B][H][T][D] bf16 ; vt: [B][H][D][T'] bf16 with t' = sigma(t) per 64-block,
// sigma(ni*16+g*4+e) = g*16 + (ni>>1)*8 + (ni&1)*4 + e  (PV-fragment-native order)
__global__ __launch_bounds__(256, 3) void proj_kernel(
    const bf16_t* __restrict__ A, const bf16_t* __restrict__ Wc,
    bf16_t* __restrict__ qo, bf16_t* __restrict__ ko, bf16_t* __restrict__ vto)
{
    __shared__ __align__(128) char smem[49152];
    // buf i at smem+i*16384: As [128 rows][64B] slot-swizzled, Bs at +8192

    const int tid  = threadIdx.x;
    const int w    = tid >> 6, lane = tid & 63;
    const int wr   = w >> 1,  wc2  = w & 1;
    const int g    = lane >> 4, c = lane & 15;
    const int bm   = blockIdx.x & 31, bn = blockIdx.x >> 5;
    const int m0   = bm * 128, n0 = bn * 128;

    f32x4 acc[4][4] = {};

    const int arow = lane >> 2;                              // 4 lanes per 64B row
    const int acol = (((lane & 3) ^ ((lane >> 3) & 3))) * 8; // pre-swizzled source slot

    #define PROJ_STAGE(buf, kt)                                                        \
        do {                                                                           \
            char* As_ = smem + (buf) * 16384;                                          \
            char* Bs_ = As_ + 8192;                                                    \
            _Pragma("unroll")                                                          \
            for (int p = 0; p < 2; ++p) {                                              \
                gload_lds16(A  + (size_t)(m0 + p*64 + w*16 + arow) * 1024 + (kt)*32 + acol, \
                            As_ + (p*64 + w*16) * 64);                                 \
                gload_lds16(Wc + (size_t)(n0 + p*64 + w*16 + arow) * 1024 + (kt)*32 + acol, \
                            Bs_ + (p*64 + w*16) * 64);                                 \
            }                                                                          \
        } while (0)

    PROJ_STAGE(0, 0);
    PROJ_STAGE(1, 1);
    int cur = 0;
    for (int kt = 0; kt < 32; ++kt) {
        if (kt == 31) asm volatile("s_waitcnt vmcnt(0)" ::: "memory");
        else          asm volatile("s_waitcnt vmcnt(4)" ::: "memory");
        __builtin_amdgcn_s_barrier();
        asm volatile("" ::: "memory");
        if (kt + 2 < 32) {
            int b2 = cur + 2; if (b2 >= 3) b2 -= 3;
            PROJ_STAGE(b2, kt + 2);
        }
        const char* As = smem + cur * 16384;
        const char* Bs = As + 8192;
        const int sw = (c >> 1) & 3;  // row-slot swizzle key
        bf16x8 af[4], bf[4];
        #pragma unroll
        for (int i = 0; i < 4; ++i) {
            af[i] = *(const bf16x8*)(As + (wr*64  + i*16 + c) * 64 + ((g ^ sw) << 4));
            bf[i] = *(const bf16x8*)(Bs + (wc2*64 + i*16 + c) * 64 + ((g ^ sw) << 4));
        }
        __builtin_amdgcn_s_setprio(1);
        #pragma unroll
        for (int i = 0; i < 4; ++i)
            #pragma unroll
            for (int j = 0; j < 4; ++j)
                acc[i][j] = __builtin_amdgcn_mfma_f32_16x16x32_bf16(af[i], bf[j], acc[i][j], 0, 0, 0);
        __builtin_amdgcn_s_setprio(0);
        cur = (cur == 2) ? 0 : cur + 1;
    }
    __syncthreads();   // all waves done with LDS bufs before epilogue reuses smem

    const int b  = m0 >> 11;
    const int t0 = m0 & 2047;

    if (n0 < 2048) {
        // q or k: [t][n] orientation in LDS, 16B-row stores of [b][h][t][d]
        bf16_t* dst = (n0 < 1024) ? qo : ko;
        const int nl0 = n0 & 1023;
        #pragma unroll
        for (int i = 0; i < 4; ++i)
            #pragma unroll
            for (int j = 0; j < 4; ++j) {
                int dl = wc2*64 + j*16 + c;
                #pragma unroll
                for (int e = 0; e < 4; ++e) {
                    int tl = wr*64 + i*16 + g*4 + e;
                    *(bf16_t*)(smem + ((tl*256 + dl*2) ^ ((tl & 7) << 4))) = (bf16_t)acc[i][j][e];
                }
            }
        __syncthreads();
        #pragma unroll
        for (int it = 0; it < 8; ++it) {
            int chunk = it * 256 + tid;          // 2048 x 16B chunks
            int tl = chunk >> 4;
            int ce = (chunk & 15) * 8;
            bf16x8 val = *(const bf16x8*)(smem + ((tl*256 + ce*2) ^ ((tl & 7) << 4)));
            int nn = nl0 + ce;
            int hh = nn >> 6, dd = nn & 63;
            *(bf16x8*)(dst + ((size_t)(b*16 + hh) * 2048 + (t0 + tl)) * 64 + dd) = val;
        }
    } else {
        // v: [n][t] orientation in LDS, sigma-permuted 16B-row stores of [b][h][d][t']
        #pragma unroll
        for (int i = 0; i < 4; ++i)
            #pragma unroll
            for (int j = 0; j < 4; ++j) {
                int dl = wc2*64 + j*16 + c;
                #pragma unroll
                for (int e = 0; e < 4; ++e) {
                    int tl = wr*64 + i*16 + g*4 + e;
                    *(bf16_t*)(smem + ((dl*256 + tl*2) ^ ((dl & 7) << 4))) = (bf16_t)acc[i][j][e];
                }
            }
        __syncthreads();
        const int nvbase = n0 - 2048;
        #pragma unroll
        for (int it = 0; it < 8; ++it) {
            int chunk = it * 256 + tid;
            int dl = chunk >> 4;
            int tl = (chunk & 15) * 8;           // permuted-local t' (0..120, step 8)
            int B64 = tl >> 6;
            int r   = tl & 63;                   // = G*16 + N8*8
            int t_a = B64*64 + ((r >> 3) & 1) * 32 + (r >> 4) * 4;  // sigma^-1 run start
            bf16x4 lo = *(const bf16x4*)(smem + ((dl*256 + t_a*2)      ^ ((dl & 7) << 4)));
            bf16x4 hi = *(const bf16x4*)(smem + ((dl*256 + (t_a+16)*2) ^ ((dl & 7) << 4)));
            bf16x8 val = __builtin_shufflevector(lo, hi, 0, 1, 2, 3, 4, 5, 6, 7);
            int nv = nvbase + dl;
            int hh = nv >> 6, dd = nv & 63;
            *(bf16x8*)(vto + (size_t)((b*16 + hh)*64 + dd) * 2048 + t0 + tl) = val;
        }
    }
    #undef PROJ_STAGE
}

// ---------------- kernel 3: causal flash attention ----------------------------
// Swapped QK^T (mfma(K,Q)) -> lane-local softmax rows; P in registers feeds PV
// via ni-block k-bijection; V stored sigma-permuted so PV reads are ds_read_b128.
// 4 waves x 16 q-rows (QBLK=64), KVBLK=64, 2-buf (32KB LDS -> 5 blocks/CU capacity).
// grid 1024, ALL blocks co-resident (4/CU <= 5 capacity). Per-CU-exact balance:
// CU slot u hosts v=0..3 with qt = {u, 31-u, (u+16)&31, 31-((u+16)&31)}; tile sum
// = 66 for every u. XCD x serves bh in {4x..4x+3} (K+V 2MB <= L2).
__global__ __launch_bounds__(256, 4) void attn_kernel(
    const bf16_t* __restrict__ qg, const bf16_t* __restrict__ kg,
    const bf16_t* __restrict__ vtg, float* __restrict__ out)
{
    __shared__ __align__(128) char smem[32768];
    // buf i at smem+i*16384: Ks [64 t][64 d] swz (8KB), Vs [64 d][64 t'] swz (8KB)

    const int tid = threadIdx.x;
    const int w = tid >> 6, lane = tid & 63;   // 4 waves
    const int g = lane >> 4, c = lane & 15;
    const int id = blockIdx.x;
    const int x  = id & 7;                     // XCD slot
    const int r  = id >> 3;                    // 0..127 within XCD
    const int u  = r & 31;                     // CU slot (round-robin fill)
    const int v  = r >> 5;                     // plane 0..3
    const int bh = x * 4 + v;
    const int u2 = (v & 1) ? (31 - ((u + (v & 2 ? 16 : 0)) & 31)) : ((u + (v & 2 ? 16 : 0)) & 31);
    const int qt = u2;                         // {u, 31-u, (u+16)&31, 31-((u+16)&31)}
    const int b = bh >> 4, h = bh & 15;

    const bf16_t* qbase = qg  + (size_t)bh * 2048 * 64;
    const bf16_t* kbase = kg  + (size_t)bh * 2048 * 64;
    const bf16_t* vbase = vtg + (size_t)bh * 64 * 2048;
    float* obase = out + (size_t)b * 2048 * 1024 + h * 64;

    const int srow = lane >> 3;                 // row within 8-row chunk
    const int scol = ((lane & 7) ^ srow) * 8;   // pre-swizzled source column (bf16)

    const int nt = qt + 1;
    const int q0 = qt * 64;

    // Q fragments (wave owns q-rows q0 + w*16 .. +15), pre-scaled into log2 domain
    bf16x8 qf[2];
    #pragma unroll
    for (int kf = 0; kf < 2; ++kf) {
        bf16x8 vq = *(const bf16x8*)(qbase + (size_t)(q0 + w*16 + c) * 64 + kf*32 + g*8);
        #pragma unroll
        for (int e = 0; e < 8; ++e) qf[kf][e] = (bf16_t)((float)vq[e] * QK_SCALE);
    }

    f32x4 oacc[4] = {};
    float mrun = -INFINITY, lrun = 0.0f;       // lrun: per-lane PARTIAL (reduced in epilogue)

    // per wave per tile: 4 gload_lds16 (2 K-chunks + 2 V-chunks of 8 rows each)
    #define ATTN_STAGE(buf, kt)                                                          \
        do {                                                                             \
            char* Kb_ = smem + (buf) * 16384;                                            \
            _Pragma("unroll")                                                            \
            for (int jj = 0; jj < 2; ++jj) {                                             \
                gload_lds16(kbase + (size_t)((kt)*64 + w*16 + jj*8 + srow) * 64 + scol,  \
                            Kb_ + (w*16 + jj*8) * 128);                                  \
                gload_lds16(vbase + (size_t)(w*16 + jj*8 + srow) * 2048 + (kt)*64 + scol,\
                            Kb_ + 8192 + (w*16 + jj*8) * 128);                           \
            }                                                                            \
        } while (0)

    ATTN_STAGE(0, 0);
    int cur = 0;

    for (int kt = 0; kt < nt; ++kt) {
        // tile-kt loads were issued a full compute phase ago -> cheap drain
        asm volatile("s_waitcnt vmcnt(0)" ::: "memory");
        __builtin_amdgcn_s_barrier();
        asm volatile("" ::: "memory");
        if (kt + 1 < nt) ATTN_STAGE(cur ^ 1, kt + 1);   // WAR-safe: all waves past barrier
        const char* Ks = smem + cur * 16384;
        const char* Vs = Ks + 8192;

        // S^T tile: mfma(A=K rows, B=Q rows) -> lane(g,c) holds
        // S[q = q0+w*16+c][k = kt*64 + ni*16 + g*4 + e], in log2 domain.
        f32x4 sacc[4];
        __builtin_amdgcn_s_setprio(1);
        #pragma unroll
        for (int ni = 0; ni < 4; ++ni) {
            int krow = ni*16 + c;
            bf16x8 k0 = *(const bf16x8*)(Ks + krow*128 + ((     g*16) ^ ((c & 7) << 4)));
            bf16x8 k1 = *(const bf16x8*)(Ks + krow*128 + ((64 + g*16) ^ ((c & 7) << 4)));
            f32x4 s0 = {0.f, 0.f, 0.f, 0.f};
            s0 = __builtin_amdgcn_mfma_f32_16x16x32_bf16(k0, qf[0], s0, 0, 0, 0);
            s0 = __builtin_amdgcn_mfma_f32_16x16x32_bf16(k1, qf[1], s0, 0, 0, 0);
            sacc[ni] = s0;
        }
        __builtin_amdgcn_s_setprio(0);

        if (kt == nt - 1) {   // the single diagonal tile: causal mask (k > q -> -inf)
            const int qloc = w*16 + c;
            #pragma unroll
            for (int ni = 0; ni < 4; ++ni)
                #pragma unroll
                for (int e = 0; e < 4; ++e)
                    if (ni*16 + g*4 + e > qloc) sacc[ni][e] = -INFINITY;
        }

        // row max: max3-shaped in-lane tree + 2 cross-group shuffles
        float pmax;
        {
            float t0_ = fmaxf(fmaxf(sacc[0][0], sacc[0][1]), sacc[0][2]);
            float t1_ = fmaxf(fmaxf(sacc[0][3], sacc[1][0]), sacc[1][1]);
            float t2_ = fmaxf(fmaxf(sacc[1][2], sacc[1][3]), sacc[2][0]);
            float t3_ = fmaxf(fmaxf(sacc[2][1], sacc[2][2]), sacc[2][3]);
            float t4_ = fmaxf(fmaxf(sacc[3][0], sacc[3][1]), sacc[3][2]);
            float u_  = fmaxf(fmaxf(t0_, t1_), t2_);
            float v_  = fmaxf(fmaxf(t3_, t4_), sacc[3][3]);
            pmax = fmaxf(u_, v_);
            pmax = fmaxf(pmax, __shfl_xor(pmax, 16));
            pmax = fmaxf(pmax, __shfl_xor(pmax, 32));
        }

        // defer-max: rescale only when some row grew by > 8 (log2 units; P <= 256)
        if (__any(pmax > mrun + 8.0f)) {
            float mnew = fmaxf(mrun, pmax);
            float sc = exp2f(mrun - mnew);        // exp2(-inf)=0 handles first tile
            float s0_ = __shfl(sc, g*4 + 0);      // redistribute to oacc row layout
            float s1_ = __shfl(sc, g*4 + 1);
            float s2_ = __shfl(sc, g*4 + 2);
            float s3_ = __shfl(sc, g*4 + 3);
            #pragma unroll
            for (int db = 0; db < 4; ++db) {
                oacc[db][0] *= s0_; oacc[db][1] *= s1_;
                oacc[db][2] *= s2_; oacc[db][3] *= s3_;
            }
            lrun *= sc;                           // sc uniform across the row's g-lanes
            mrun = mnew;
        }

        // P = exp2(S - m), packed straight into MFMA A-fragments; lrun stays partial
        float psum = 0.f;
        bf16x8 palo, pahi;
        #pragma unroll
        for (int ni = 0; ni < 4; ++ni)
            #pragma unroll
            for (int e = 0; e < 4; ++e) {
                float pv = exp2f(sacc[ni][e] - mrun);
                psum += pv;
                if (ni < 2) palo[(ni & 1)*4 + e] = (bf16_t)pv;
                else        pahi[(ni & 1)*4 + e] = (bf16_t)pv;
            }
        lrun += psum;

        // O += P V : sigma-stored V -> two b128 reads per db, fragment-native order
        __builtin_amdgcn_s_setprio(1);
        #pragma unroll
        for (int db = 0; db < 4; ++db) {
            int vrow = db*16 + c;
            bf16x8 vlo = *(const bf16x8*)(Vs + vrow*128 + ((g*32     ) ^ ((c & 7) << 4)));
            bf16x8 vhi = *(const bf16x8*)(Vs + vrow*128 + ((g*32 + 16) ^ ((c & 7) << 4)));
            oacc[db] = __builtin_amdgcn_mfma_f32_16x16x32_bf16(palo, vlo, oacc[db], 0, 0, 0);
            oacc[db] = __builtin_amdgcn_mfma_f32_16x16x32_bf16(pahi, vhi, oacc[db], 0, 0, 0);
        }
        __builtin_amdgcn_s_setprio(0);

        cur ^= 1;
    }

    // epilogue: finish lrun row-reduction once, normalize, fp32 store [b][t][h*64+d]
    lrun += __shfl_xor(lrun, 16);
    lrun += __shfl_xor(lrun, 32);
    float inv[4];
    #pragma unroll
    for (int e = 0; e < 4; ++e) inv[e] = 1.0f / __shfl(lrun, g*4 + e);
    #pragma unroll
    for (int e = 0; e < 4; ++e) {
        size_t trow = (size_t)(q0 + w*16 + g*4 + e);
        #pragma unroll
        for (int db = 0; db < 4; ++db)
            obase[trow * 1024 + db*16 + c] = oacc[db][e] * inv[e];
    }
    #undef ATTN_STAGE
}

extern "C" void kernel_launch(void* const* d_in, const int* in_sizes, int n_in,
                              void* d_out, int out_size, void* d_ws, size_t ws_size,
                              hipStream_t stream) {
    const float* emb = (const float*)d_in[0];
    const float* wq  = (const float*)d_in[1];
    const float* wk  = (const float*)d_in[2];
    const float* wv  = (const float*)d_in[3];
    float* out = (float*)d_out;

    char* ws = (char*)d_ws;
    bf16_t* embb = (bf16_t*)ws;                          // 8 MB  [4096][1024]
    bf16_t* wcat = (bf16_t*)(ws + (size_t) 8*1024*1024); // 6 MB  [3072][1024]
    bf16_t* qb   = (bf16_t*)(ws + (size_t)14*1024*1024); // 8 MB  [BH][T][D]
    bf16_t* kb   = (bf16_t*)(ws + (size_t)22*1024*1024); // 8 MB  [BH][T][D]
    bf16_t* vtb  = (bf16_t*)(ws + (size_t)30*1024*1024); // 8 MB  [BH][D][T'] sigma-permuted

    convert_kernel<<<3584, 256, 0, stream>>>(emb, wq, wk, wv, embb, wcat);
    proj_kernel<<<768, 256, 0, stream>>>(embb, wcat, qb, kb, vtb);
    attn_kernel<<<1024, 256, 0, stream>>>(qb, kb, vtb, out);
}